// Round 2
// baseline (362.654 us; speedup 1.0000x reference)
//
#include <hip/hip_runtime.h>
#include <math.h>

#define NROWS 65536
#define PER 64
#define BIMG 1024
#define NCLS 36
#define OBJ_DIM 192
#define EMB 200
#define POSD 128
#define HID 1024
#define EPSV 1e-5f

#define KP 384            // padded K for GEMM1 (355 real -> 384)
#define XSTR 392          // Xs LDS row stride in fp16 units
#define GCSTR 72          // Gc row stride in fp16 units (64 + 8)
#define W2KP 1024         // W2T k stride

// X column layout (alignment-friendly; W1fT rows permuted to match):
//   [0,192)   features
//   [192,320) pos (relu(h @ pos_W + pos_b))        <- dec1_W rows 392..519
//   [320,355) distribution (folded obj_embed)      <- Fold rows 0..34
//   [355,384) zero pad

typedef __attribute__((ext_vector_type(8))) _Float16 f16x8;
typedef __attribute__((ext_vector_type(4))) _Float16 f16x4;
typedef __attribute__((ext_vector_type(4))) float f32x4;

// ---------------- fold: Fold[35][1024] = obj_embed_W(35x200) @ dec1_W[192:392](200x1024) ----
__global__ __launch_bounds__(256) void k_fold(
    const float* __restrict__ obj_embed_W, const float* __restrict__ dec1_W,
    float* __restrict__ Fold)
{
    int e = blockIdx.x;                               // 0..34
    int h = blockIdx.y * 256 + threadIdx.x;           // 0..1023
    const float* A  = obj_embed_W + (size_t)e * EMB;  // uniform -> s_load
    const float* Bp = dec1_W + (size_t)192 * HID + h;
    float acc = 0.f;
#pragma unroll 8
    for (int j = 0; j < EMB; ++j)
        acc = fmaf(A[j], Bp[(size_t)j * HID], acc);
    Fold[(size_t)e * HID + h] = acc;
}

// ---------------- prep: fused+scaled W1f^T (fp16), W2^T (fp16), bias vector ----------------
__global__ __launch_bounds__(256) void k_prep(
    const float* __restrict__ Fold, const float* __restrict__ dec1_W,
    const float* __restrict__ dec1_b,
    const float* __restrict__ bn1k_g, const float* __restrict__ bn1k_b,
    const float* __restrict__ bn1k_m, const float* __restrict__ bn1k_v,
    const float* __restrict__ dec2_W,
    _Float16* __restrict__ W1fT, _Float16* __restrict__ W2T,
    float* __restrict__ bs)
{
    int idx = blockIdx.x * 256 + threadIdx.x;
    if (idx < HID * KP) {
        int h = idx / KP, k = idx % KP;
        float sc = rsqrtf(bn1k_v[h] + EPSV) * bn1k_g[h];
        float v;
        if (k < 192)      v = dec1_W[(size_t)k * HID + h];
        else if (k < 320) v = dec1_W[(size_t)(k + 200) * HID + h];   // pos rows 392..519
        else if (k < 355) v = Fold[(size_t)(k - 320) * HID + h];     // folded obj_embed
        else              v = 0.f;
        W1fT[(size_t)h * KP + k] = (_Float16)(v * sc);
        if (k == 0) bs[h] = (dec1_b[h] - bn1k_m[h]) * sc + bn1k_b[h];
    } else {
        int j = idx - HID * KP;           // 48 * 1024 region
        if (j < 48 * W2KP) {
            int c = j / W2KP, h2 = j % W2KP;
            float v = (c < NCLS) ? dec2_W[(size_t)h2 * NCLS + c] : 0.f;
            W2T[j] = (_Float16)v;
        }
    }
}

// ---------------- main fused kernel: 64 rows/block, 8 waves, fp16 MFMA ----------------
// Wave split: w = wv&3 -> hidden sub-block (as before); g = wv>>2 ->
//   GEMM1: row half (rows 32g..32g+31, n = 2g+nn)
//   GEMM2: k half (kl = 32g + 8lq), partials merged through Lst.
__global__ __launch_bounds__(512, 4) void k_main(
    const float* __restrict__ distribution, const float* __restrict__ features,
    const float* __restrict__ boxes,
    const float* __restrict__ bn4_g, const float* __restrict__ bn4_b,
    const float* __restrict__ bn4_m, const float* __restrict__ bn4_v,
    const float* __restrict__ pos_W, const float* __restrict__ pos_b,
    const _Float16* __restrict__ W1fT, const _Float16* __restrict__ W2T,
    const float* __restrict__ bs, const float* __restrict__ dec2_b,
    float* __restrict__ out)
{
    __shared__ __align__(16) char smem[62720];
    _Float16* Xs = (_Float16*)smem;                // 64*392 fp16 = 50176 B
    _Float16* Gc = (_Float16*)(smem + 50176);      // 64*72 fp16 = 9216 B
    float* Lst   = (float*)(smem + 50176);         // aliases Gc (64*49*4 = 12544 B)

    int t = threadIdx.x;
    int row0 = blockIdx.x * PER;

    // ---- stage X as fp16 into Xs, all loads coalesced/vectorized ----
    {
        // features: cols [0,192). 64 rows x 48 float4 = 3072 loads, fully coalesced.
        const float4* F4 = (const float4*)(features + (size_t)row0 * OBJ_DIM);
#pragma unroll
        for (int it = 0; it < 6; ++it) {
            int li = t + 512 * it;                 // 0..3071
            int r = li / 48, c4 = li % 48;
            float4 v = F4[li];
            f16x4 h4;
            h4[0] = (_Float16)v.x; h4[1] = (_Float16)v.y;
            h4[2] = (_Float16)v.z; h4[3] = (_Float16)v.w;
            *(f16x4*)&Xs[r * XSTR + c4 * 4] = h4;
        }
        // distribution + zero pad: cols [320,384). 64 rows x 8 groups of 8.
        const float* D = distribution + (size_t)row0 * (NCLS - 1);
        {
            int li = t;                            // 0..511
            int r = li >> 3, gq = li & 7;
            f16x8 v8;
#pragma unroll
            for (int e = 0; e < 8; ++e) {
                int c = gq * 8 + e;                // 0..63
                v8[e] = (c < 35) ? (_Float16)D[(size_t)r * 35 + c] : (_Float16)0.f;
            }
            *(f16x8*)&Xs[r * XSTR + 320 + gq * 8] = v8;
        }
        // pos: cols [192,320). thread (r, kq) computes 16 cols, aligned f16x8 stores.
        int r = t >> 3, kq = t & 7;
        int grow = row0 + r;
        const float* bx = boxes + (size_t)grow * 5;
        float x1 = bx[1], y1 = bx[2], x2 = bx[3], y2 = bx[4];
        float w = x2 - x1 + 1.f, hh = y2 - y1 + 1.f;
        float cs[4] = {x1 + 0.5f * w, y1 + 0.5f * hh, w, hh};
        float hv[4];
#pragma unroll
        for (int i = 0; i < 4; i++)
            hv[i] = (cs[i] - bn4_m[i]) * rsqrtf(bn4_v[i] + EPSV) * bn4_g[i] + bn4_b[i];
#pragma unroll
        for (int jb = 0; jb < 2; ++jb) {
            int j0 = kq * 16 + jb * 8;
            f16x8 v8;
#pragma unroll
            for (int e = 0; e < 8; ++e) {
                int j = j0 + e;
                float p = pos_b[j];
                p = fmaf(hv[0], pos_W[j], p);
                p = fmaf(hv[1], pos_W[POSD + j], p);
                p = fmaf(hv[2], pos_W[2 * POSD + j], p);
                p = fmaf(hv[3], pos_W[3 * POSD + j], p);
                v8[e] = (_Float16)fmaxf(p, 0.f);
            }
            *(f16x8*)&Xs[r * XSTR + 192 + j0] = v8;
        }
    }
    __syncthreads();

    int wv = t >> 6, lane = t & 63, lr = lane & 15, lq = lane >> 4;
    int w = wv & 3, g = wv >> 2;       // hidden sub-block / row-or-k half

    f32x4 Lg[3];                       // partial logit frags (k-half g)
#pragma unroll
    for (int n = 0; n < 3; n++) Lg[n] = (f32x4){0.f, 0.f, 0.f, 0.f};

    for (int c0 = 0; c0 < 4; ++c0) {   // hidden chunks of 256
        int H0 = c0 * 256;
        const _Float16* wp = W1fT + (size_t)(H0 + 16 * w + lr) * KP;
        f32x4 C[4][2];
#pragma unroll
        for (int j = 0; j < 4; j++)
#pragma unroll
            for (int n = 0; n < 2; n++) C[j][n] = (f32x4){0.f, 0.f, 0.f, 0.f};

        // ---- GEMM1 K-loop: no barriers, depth-1 register prefetch ----
        f16x8 ahc[4], bhc[2];
        {
            int k0 = lq * 8;
#pragma unroll
            for (int j = 0; j < 4; j++) ahc[j] = *(const f16x8*)(wp + (size_t)(64 * j) * KP + k0);
#pragma unroll
            for (int n = 0; n < 2; n++) bhc[n] = *(const f16x8*)&Xs[(16 * (2 * g + n) + lr) * XSTR + k0];
        }
        for (int ks = 0; ks < 11; ++ks) {
            f16x8 ahn[4], bhn[2];
            {
                int k0 = (ks + 1) * 32 + lq * 8;
#pragma unroll
                for (int j = 0; j < 4; j++) ahn[j] = *(const f16x8*)(wp + (size_t)(64 * j) * KP + k0);
#pragma unroll
                for (int n = 0; n < 2; n++) bhn[n] = *(const f16x8*)&Xs[(16 * (2 * g + n) + lr) * XSTR + k0];
            }
#pragma unroll
            for (int j = 0; j < 4; j++)
#pragma unroll
                for (int n = 0; n < 2; n++)
                    C[j][n] = __builtin_amdgcn_mfma_f32_16x16x32_f16(ahc[j], bhc[n], C[j][n], 0, 0, 0);
#pragma unroll
            for (int j = 0; j < 4; j++) ahc[j] = ahn[j];
#pragma unroll
            for (int n = 0; n < 2; n++) bhc[n] = bhn[n];
        }
#pragma unroll
        for (int j = 0; j < 4; j++)
#pragma unroll
            for (int n = 0; n < 2; n++)
                C[j][n] = __builtin_amdgcn_mfma_f32_16x16x32_f16(ahc[j], bhc[n], C[j][n], 0, 0, 0);

        // ---- transform + GEMM2, 4 sub-rounds of 64 hidden ----
        for (int j = 0; j < 4; ++j) {
            __syncthreads();           // Gc free (previous GEMM2 done)
            int hb = H0 + 16 * (w + 4 * j) + 4 * lq;
            f32x4 bsv = *(const f32x4*)(bs + hb);
#pragma unroll
            for (int n = 0; n < 2; n++) {
                f16x4 g4;
#pragma unroll
                for (int e = 0; e < 4; ++e)
                    g4[e] = (_Float16)fmaxf(C[j][n][e] + bsv[e], 0.f);
                *(f16x4*)&Gc[(16 * (2 * g + n) + lr) * GCSTR + 16 * w + 4 * lq] = g4;
            }
            __syncthreads();           // Gc filled
            {
                int kl = 32 * g + lq * 8;          // k-half split across wave groups
                f16x8 a2 = *(const f16x8*)&Gc[(16 * w + lr) * GCSTR + kl];
                int hg = H0 + 64 * j + kl;
#pragma unroll
                for (int n = 0; n < 3; n++) {
                    f16x8 b2 = *(const f16x8*)(W2T + (size_t)(16 * n + lr) * W2KP + hg);
                    Lg[n] = __builtin_amdgcn_mfma_f32_16x16x32_f16(a2, b2, Lg[n], 0, 0, 0);
                }
            }
        }
    }

    __syncthreads();                   // Gc region now reused as logit stash
    // merge the two k-half partials: g=1 writes, then g=0 adds.
    if (g == 1) {
#pragma unroll
        for (int n = 0; n < 3; n++)
#pragma unroll
            for (int e = 0; e < 4; ++e)
                Lst[(16 * w + 4 * lq + e) * 49 + 16 * n + lr] = Lg[n][e];
    }
    __syncthreads();
    if (g == 0) {
#pragma unroll
        for (int n = 0; n < 3; n++)
#pragma unroll
            for (int e = 0; e < 4; ++e)
                Lst[(16 * w + 4 * lq + e) * 49 + 16 * n + lr] += Lg[n][e];
    }
    __syncthreads();

    // ---- softmax head + fused per-image human argmax (t<64 == wave 0) ----
    if (t < 64) {
        int row = row0 + t;
        float lg[36];
#pragma unroll
        for (int c = 1; c < 36; ++c) lg[c] = Lst[t * 49 + c] + dec2_b[c];
        float m = lg[1];
#pragma unroll
        for (int c = 2; c < 36; ++c) m = fmaxf(m, lg[c]);
        float d[35];
        float s = 0.f;
#pragma unroll
        for (int c = 1; c < 36; ++c) { float e = expf(lg[c] - m); d[c - 1] = e; s += e; }
        float inv = 1.0f / s;
        float* dout = out + (size_t)row * 35;
#pragma unroll
        for (int j = 0; j < 35; ++j) dout[j] = d[j] * inv;

        // per-row argmax over dist cols 1..34 (first-occurrence), label = distcol+1
        float best = -1.f; int bi = 1;
#pragma unroll
        for (int c = 1; c < 35; ++c) {
            float v = d[c] * inv;
            if (v > best) { best = v; bi = c; }
        }

        // block == image: argmax over dist[:,0] across the 64 lanes
        float v0 = d[0] * inv;
        float mv = v0; int mi = t;
#pragma unroll
        for (int off = 32; off > 0; off >>= 1) {
            float ov = __shfl_down(mv, off);
            int   oi = __shfl_down(mi, off);
            if (ov > mv || (ov == mv && oi < mi)) { mv = ov; mi = oi; }
        }
        int human = __shfl(mi, 0);     // local row of the human
        bool isH = (t == human);
        out[(size_t)NROWS * 35 + row] = isH ? v0 : best;
        out[(size_t)NROWS * 36 + row] = isH ? 1.0f : (float)(bi + 1);
        if (t == 0) out[(size_t)NROWS * 37 + blockIdx.x] = (float)(row0 + human);
    }
}

extern "C" void kernel_launch(void* const* d_in, const int* in_sizes, int n_in,
                              void* d_out, int out_size, void* d_ws, size_t ws_size,
                              hipStream_t stream)
{
    (void)in_sizes; (void)n_in; (void)out_size; (void)ws_size;
    const float* distribution = (const float*)d_in[0];
    const float* features     = (const float*)d_in[1];
    const float* boxes        = (const float*)d_in[2];
    const float* obj_embed_W  = (const float*)d_in[3];
    const float* bn4_g        = (const float*)d_in[4];
    const float* bn4_b        = (const float*)d_in[5];
    const float* bn4_m        = (const float*)d_in[6];
    const float* bn4_v        = (const float*)d_in[7];
    const float* pos_W        = (const float*)d_in[8];
    const float* pos_b        = (const float*)d_in[9];
    const float* dec1_W       = (const float*)d_in[10];
    const float* dec1_b       = (const float*)d_in[11];
    const float* bn1k_g       = (const float*)d_in[12];
    const float* bn1k_b       = (const float*)d_in[13];
    const float* bn1k_m       = (const float*)d_in[14];
    const float* bn1k_v       = (const float*)d_in[15];
    const float* dec2_W       = (const float*)d_in[16];
    const float* dec2_b       = (const float*)d_in[17];

    float* out = (float*)d_out;

    // ws layout (~1.01 MB)
    _Float16* W1fT = (_Float16*)d_ws;                      // 1024*384 fp16
    _Float16* W2T  = W1fT + (size_t)HID * KP;              // 48*1024 fp16
    float*    bsv  = (float*)(W2T + (size_t)48 * W2KP);    // 1024 f32
    float*    Fold = bsv + HID;                            // 35*1024 f32

    k_fold<<<dim3(35, 4), 256, 0, stream>>>(obj_embed_W, dec1_W, Fold);

    int prep_elems = HID * KP + 48 * W2KP;
    k_prep<<<(prep_elems + 255) / 256, 256, 0, stream>>>(
        Fold, dec1_W, dec1_b, bn1k_g, bn1k_b, bn1k_m, bn1k_v, dec2_W,
        W1fT, W2T, bsv);

    k_main<<<BIMG, 512, 0, stream>>>(
        distribution, features, boxes, bn4_g, bn4_b, bn4_m, bn4_v, pos_W, pos_b,
        W1fT, W2T, bsv, dec2_b, out);
}

// Round 3
// 293.478 us; speedup vs baseline: 1.2357x; 1.2357x over previous
//
#include <hip/hip_runtime.h>
#include <math.h>

#define NROWS 65536
#define PER 64
#define BIMG 1024
#define NCLS 36
#define OBJ_DIM 192
#define EMB 200
#define POSD 128
#define HID 1024
#define EPSV 1e-5f

#define KP 384            // padded K for GEMM1 (355 real -> 384)
#define XSTR 392          // Xs LDS row stride in fp16 units
#define GCSTR 72          // Gc row stride in fp16 units (64 + 8)
#define W2KP 1024         // W2T k stride

// X column layout (alignment-friendly; W1fT rows permuted to match):
//   [0,192)   features
//   [192,320) pos (relu(h @ pos_W + pos_b))        <- dec1_W rows 392..519
//   [320,355) distribution (folded obj_embed)      <- Fold rows 0..34
//   [355,384) zero pad

typedef __attribute__((ext_vector_type(8))) _Float16 f16x8;
typedef __attribute__((ext_vector_type(4))) _Float16 f16x4;
typedef __attribute__((ext_vector_type(4))) float f32x4;

// ---------------- fold: Fold[35][1024] = obj_embed_W(35x200) @ dec1_W[192:392](200x1024) ----
__global__ __launch_bounds__(256) void k_fold(
    const float* __restrict__ obj_embed_W, const float* __restrict__ dec1_W,
    float* __restrict__ Fold)
{
    int e = blockIdx.x;                               // 0..34
    int h = blockIdx.y * 256 + threadIdx.x;           // 0..1023
    const float* A  = obj_embed_W + (size_t)e * EMB;  // uniform -> s_load
    const float* Bp = dec1_W + (size_t)192 * HID + h;
    float acc = 0.f;
#pragma unroll 8
    for (int j = 0; j < EMB; ++j)
        acc = fmaf(A[j], Bp[(size_t)j * HID], acc);
    Fold[(size_t)e * HID + h] = acc;
}

// ---------------- prep: fused+scaled W1f^T (fp16), W2^T (fp16), bias vector ----------------
__global__ __launch_bounds__(256) void k_prep(
    const float* __restrict__ Fold, const float* __restrict__ dec1_W,
    const float* __restrict__ dec1_b,
    const float* __restrict__ bn1k_g, const float* __restrict__ bn1k_b,
    const float* __restrict__ bn1k_m, const float* __restrict__ bn1k_v,
    const float* __restrict__ dec2_W,
    _Float16* __restrict__ W1fT, _Float16* __restrict__ W2T,
    float* __restrict__ bs)
{
    int idx = blockIdx.x * 256 + threadIdx.x;
    if (idx < HID * KP) {
        int h = idx / KP, k = idx % KP;
        float sc = rsqrtf(bn1k_v[h] + EPSV) * bn1k_g[h];
        float v;
        if (k < 192)      v = dec1_W[(size_t)k * HID + h];
        else if (k < 320) v = dec1_W[(size_t)(k + 200) * HID + h];   // pos rows 392..519
        else if (k < 355) v = Fold[(size_t)(k - 320) * HID + h];     // folded obj_embed
        else              v = 0.f;
        W1fT[(size_t)h * KP + k] = (_Float16)(v * sc);
        if (k == 0) bs[h] = (dec1_b[h] - bn1k_m[h]) * sc + bn1k_b[h];
    } else {
        int j = idx - HID * KP;           // 48 * 1024 region
        if (j < 48 * W2KP) {
            int c = j / W2KP, h2 = j % W2KP;
            float v = (c < NCLS) ? dec2_W[(size_t)h2 * NCLS + c] : 0.f;
            W2T[j] = (_Float16)v;
        }
    }
}

// ---------------- main fused kernel: 64 rows/block, 4 waves, fp16 MFMA ----------------
// Gc double-buffered (1 barrier per GEMM2 sub-round), depth-2 W1fT prefetch,
// W2T fragments pipelined one sub-round ahead.
__global__ __launch_bounds__(256, 2) void k_main(
    const float* __restrict__ distribution, const float* __restrict__ features,
    const float* __restrict__ boxes,
    const float* __restrict__ bn4_g, const float* __restrict__ bn4_b,
    const float* __restrict__ bn4_m, const float* __restrict__ bn4_v,
    const float* __restrict__ pos_W, const float* __restrict__ pos_b,
    const _Float16* __restrict__ W1fT, const _Float16* __restrict__ W2T,
    const float* __restrict__ bs, const float* __restrict__ dec2_b,
    float* __restrict__ out)
{
    __shared__ __align__(16) char smem[68608];
    _Float16* Xs = (_Float16*)smem;                // 64*392 fp16 = 50176 B
    // Gc buffers: [50176, 59392) and [59392, 68608)
    float* Lst   = (float*)(smem + 50176);         // aliases Gc bufs (64*49*4 = 12544 B)

    int t = threadIdx.x;
    int row0 = blockIdx.x * PER;
    int wv = t >> 6, lane = t & 63, lr = lane & 15, lq = lane >> 4;

    // ---- early W2T prefetch for sub-round 0 (independent of everything) ----
    f16x8 w2c[3][2];
#pragma unroll
    for (int n = 0; n < 3; n++)
#pragma unroll
        for (int ks2 = 0; ks2 < 2; ks2++)
            w2c[n][ks2] = *(const f16x8*)(W2T + (size_t)(16 * n + lr) * W2KP + 32 * ks2 + 8 * lq);

    // ---- stage X as fp16 into Xs, all loads coalesced/vectorized ----
    {
        // features: cols [0,192). 64 rows x 48 float4 = 3072 loads, fully coalesced.
        const float4* F4 = (const float4*)(features + (size_t)row0 * OBJ_DIM);
#pragma unroll
        for (int it = 0; it < 12; ++it) {
            int li = t + 256 * it;                 // 0..3071
            int r = li / 48, c4 = li % 48;
            float4 v = F4[li];
            f16x4 h4;
            h4[0] = (_Float16)v.x; h4[1] = (_Float16)v.y;
            h4[2] = (_Float16)v.z; h4[3] = (_Float16)v.w;
            *(f16x4*)&Xs[r * XSTR + c4 * 4] = h4;
        }
        // distribution + zero pad: cols [320,384). 64 rows x 8 groups of 8.
        const float* D = distribution + (size_t)row0 * (NCLS - 1);
#pragma unroll
        for (int it = 0; it < 2; ++it) {
            int li = t + 256 * it;                 // 0..511
            int r = li >> 3, gq = li & 7;
            f16x8 v8;
#pragma unroll
            for (int e = 0; e < 8; ++e) {
                int c = gq * 8 + e;                // 0..63
                v8[e] = (c < 35) ? (_Float16)D[(size_t)r * 35 + c] : (_Float16)0.f;
            }
            *(f16x8*)&Xs[r * XSTR + 320 + gq * 8] = v8;
        }
        // pos: cols [192,320). thread (r, kq) computes 32 cols, aligned f16x8 stores.
        int r = t >> 2, kq = t & 3;
        int grow = row0 + r;
        const float* bx = boxes + (size_t)grow * 5;
        float x1 = bx[1], y1 = bx[2], x2 = bx[3], y2 = bx[4];
        float w = x2 - x1 + 1.f, hh = y2 - y1 + 1.f;
        float cs[4] = {x1 + 0.5f * w, y1 + 0.5f * hh, w, hh};
        float hv[4];
#pragma unroll
        for (int i = 0; i < 4; i++)
            hv[i] = (cs[i] - bn4_m[i]) * rsqrtf(bn4_v[i] + EPSV) * bn4_g[i] + bn4_b[i];
#pragma unroll
        for (int jb = 0; jb < 4; ++jb) {
            int j0 = kq * 32 + jb * 8;
            f16x8 v8;
#pragma unroll
            for (int e = 0; e < 8; ++e) {
                int j = j0 + e;
                float p = pos_b[j];
                p = fmaf(hv[0], pos_W[j], p);
                p = fmaf(hv[1], pos_W[POSD + j], p);
                p = fmaf(hv[2], pos_W[2 * POSD + j], p);
                p = fmaf(hv[3], pos_W[3 * POSD + j], p);
                v8[e] = (_Float16)fmaxf(p, 0.f);
            }
            *(f16x8*)&Xs[r * XSTR + 192 + j0] = v8;
        }
    }
    __syncthreads();

    f32x4 Lg[3];                       // logit frags: rows 16wv..+15 x classes 48
#pragma unroll
    for (int n = 0; n < 3; n++) Lg[n] = (f32x4){0.f, 0.f, 0.f, 0.f};

    for (int c0 = 0; c0 < 4; ++c0) {   // hidden chunks of 256
        int H0 = c0 * 256;
        const _Float16* wp = W1fT + (size_t)(H0 + 16 * wv + lr) * KP;

        // hoist bias-vector loads for this chunk's 4 sub-rounds
        f32x4 bsv4[4];
#pragma unroll
        for (int j = 0; j < 4; j++)
            bsv4[j] = *(const f32x4*)(bs + H0 + 16 * (wv + 4 * j) + 4 * lq);

        f32x4 C[4][4];
#pragma unroll
        for (int j = 0; j < 4; j++)
#pragma unroll
            for (int n = 0; n < 4; n++) C[j][n] = (f32x4){0.f, 0.f, 0.f, 0.f};

        // ---- GEMM1 K-loop: depth-2 prefetch on A (L2), depth-1 on B (LDS) ----
        f16x8 aA[4], aB[4], b0[4];
        {
            int k0 = lq * 8;
#pragma unroll
            for (int j2 = 0; j2 < 4; j2++) aA[j2] = *(const f16x8*)(wp + (size_t)(64 * j2) * KP + k0);
#pragma unroll
            for (int n = 0; n < 4; n++) b0[n] = *(const f16x8*)&Xs[(16 * n + lr) * XSTR + k0];
#pragma unroll
            for (int j2 = 0; j2 < 4; j2++) aB[j2] = *(const f16x8*)(wp + (size_t)(64 * j2) * KP + 32 + k0);
        }
#pragma unroll
        for (int ks = 0; ks < 10; ++ks) {
            f16x8 aC[4], b1[4];
            int k2 = (ks + 2) * 32 + lq * 8;
            int k1 = (ks + 1) * 32 + lq * 8;
#pragma unroll
            for (int j2 = 0; j2 < 4; j2++) aC[j2] = *(const f16x8*)(wp + (size_t)(64 * j2) * KP + k2);
#pragma unroll
            for (int n = 0; n < 4; n++) b1[n] = *(const f16x8*)&Xs[(16 * n + lr) * XSTR + k1];
#pragma unroll
            for (int j2 = 0; j2 < 4; j2++)
#pragma unroll
                for (int n = 0; n < 4; n++)
                    C[j2][n] = __builtin_amdgcn_mfma_f32_16x16x32_f16(aA[j2], b0[n], C[j2][n], 0, 0, 0);
#pragma unroll
            for (int j2 = 0; j2 < 4; j2++) { aA[j2] = aB[j2]; aB[j2] = aC[j2]; }
#pragma unroll
            for (int n = 0; n < 4; n++) b0[n] = b1[n];
        }
        {   // tail: K-steps 10 (aA,b0) and 11 (aB,b1)
            f16x8 b1[4];
            int k1 = 11 * 32 + lq * 8;
#pragma unroll
            for (int n = 0; n < 4; n++) b1[n] = *(const f16x8*)&Xs[(16 * n + lr) * XSTR + k1];
#pragma unroll
            for (int j2 = 0; j2 < 4; j2++)
#pragma unroll
                for (int n = 0; n < 4; n++)
                    C[j2][n] = __builtin_amdgcn_mfma_f32_16x16x32_f16(aA[j2], b0[n], C[j2][n], 0, 0, 0);
#pragma unroll
            for (int j2 = 0; j2 < 4; j2++)
#pragma unroll
                for (int n = 0; n < 4; n++)
                    C[j2][n] = __builtin_amdgcn_mfma_f32_16x16x32_f16(aB[j2], b1[n], C[j2][n], 0, 0, 0);
        }

        // ---- transform + GEMM2, 4 sub-rounds of 64 hidden, double-buffered Gc ----
#pragma unroll
        for (int j = 0; j < 4; ++j) {
            _Float16* Gcb = (_Float16*)(smem + 50176 + 9216 * (j & 1));
#pragma unroll
            for (int n = 0; n < 4; n++) {
                f16x4 g4;
#pragma unroll
                for (int e = 0; e < 4; ++e)
                    g4[e] = (_Float16)fmaxf(C[j][n][e] + bsv4[j][e], 0.f);
                *(f16x4*)&Gcb[(16 * n + lr) * GCSTR + 16 * wv + 4 * lq] = g4;
            }
            __syncthreads();           // Gc[buf] filled; prior reads of this buf were 2 sub-rounds ago
            f16x8 a2[2];
#pragma unroll
            for (int ks2 = 0; ks2 < 2; ks2++)
                a2[ks2] = *(const f16x8*)&Gcb[(16 * wv + lr) * GCSTR + 32 * ks2 + 8 * lq];
            // prefetch next sub-round's W2T fragments (hg = 64*(s+1) + kl)
            int s = c0 * 4 + j;
            int hgn = (s < 15) ? 64 * (s + 1) : 0;
            f16x8 w2n[3][2];
#pragma unroll
            for (int n = 0; n < 3; n++)
#pragma unroll
                for (int ks2 = 0; ks2 < 2; ks2++)
                    w2n[n][ks2] = *(const f16x8*)(W2T + (size_t)(16 * n + lr) * W2KP + hgn + 32 * ks2 + 8 * lq);
#pragma unroll
            for (int ks2 = 0; ks2 < 2; ks2++)
#pragma unroll
                for (int n = 0; n < 3; n++)
                    Lg[n] = __builtin_amdgcn_mfma_f32_16x16x32_f16(a2[ks2], w2c[n][ks2], Lg[n], 0, 0, 0);
#pragma unroll
            for (int n = 0; n < 3; n++)
#pragma unroll
                for (int ks2 = 0; ks2 < 2; ks2++)
                    w2c[n][ks2] = w2n[n][ks2];
        }
    }

    __syncthreads();                   // last GEMM2 reads done; Gc region becomes logit stash
#pragma unroll
    for (int n = 0; n < 3; n++)
#pragma unroll
        for (int e = 0; e < 4; ++e)
            Lst[(16 * wv + 4 * lq + e) * 49 + 16 * n + lr] = Lg[n][e];
    __syncthreads();

    // ---- softmax head + fused per-image human argmax (t<64 == wave 0) ----
    if (t < 64) {
        int row = row0 + t;
        float lg[36];
#pragma unroll
        for (int c = 1; c < 36; ++c) lg[c] = Lst[t * 49 + c] + dec2_b[c];
        float m = lg[1];
#pragma unroll
        for (int c = 2; c < 36; ++c) m = fmaxf(m, lg[c]);
        float d[35];
        float s = 0.f;
#pragma unroll
        for (int c = 1; c < 36; ++c) { float e = expf(lg[c] - m); d[c - 1] = e; s += e; }
        float inv = 1.0f / s;
        float* dout = out + (size_t)row * 35;
#pragma unroll
        for (int j = 0; j < 35; ++j) dout[j] = d[j] * inv;

        // per-row argmax over dist cols 1..34 (first-occurrence), label = distcol+1
        float best = -1.f; int bi = 1;
#pragma unroll
        for (int c = 1; c < 35; ++c) {
            float v = d[c] * inv;
            if (v > best) { best = v; bi = c; }
        }

        // block == image: argmax over dist[:,0] across the 64 lanes
        float v0 = d[0] * inv;
        float mv = v0; int mi = t;
#pragma unroll
        for (int off = 32; off > 0; off >>= 1) {
            float ov = __shfl_down(mv, off);
            int   oi = __shfl_down(mi, off);
            if (ov > mv || (ov == mv && oi < mi)) { mv = ov; mi = oi; }
        }
        int human = __shfl(mi, 0);     // local row of the human
        bool isH = (t == human);
        out[(size_t)NROWS * 35 + row] = isH ? v0 : best;
        out[(size_t)NROWS * 36 + row] = isH ? 1.0f : (float)(bi + 1);
        if (t == 0) out[(size_t)NROWS * 37 + blockIdx.x] = (float)(row0 + human);
    }
}

extern "C" void kernel_launch(void* const* d_in, const int* in_sizes, int n_in,
                              void* d_out, int out_size, void* d_ws, size_t ws_size,
                              hipStream_t stream)
{
    (void)in_sizes; (void)n_in; (void)out_size; (void)ws_size;
    const float* distribution = (const float*)d_in[0];
    const float* features     = (const float*)d_in[1];
    const float* boxes        = (const float*)d_in[2];
    const float* obj_embed_W  = (const float*)d_in[3];
    const float* bn4_g        = (const float*)d_in[4];
    const float* bn4_b        = (const float*)d_in[5];
    const float* bn4_m        = (const float*)d_in[6];
    const float* bn4_v        = (const float*)d_in[7];
    const float* pos_W        = (const float*)d_in[8];
    const float* pos_b        = (const float*)d_in[9];
    const float* dec1_W       = (const float*)d_in[10];
    const float* dec1_b       = (const float*)d_in[11];
    const float* bn1k_g       = (const float*)d_in[12];
    const float* bn1k_b       = (const float*)d_in[13];
    const float* bn1k_m       = (const float*)d_in[14];
    const float* bn1k_v       = (const float*)d_in[15];
    const float* dec2_W       = (const float*)d_in[16];
    const float* dec2_b       = (const float*)d_in[17];

    float* out = (float*)d_out;

    // ws layout (~1.01 MB)
    _Float16* W1fT = (_Float16*)d_ws;                      // 1024*384 fp16
    _Float16* W2T  = W1fT + (size_t)HID * KP;              // 48*1024 fp16
    float*    bsv  = (float*)(W2T + (size_t)48 * W2KP);    // 1024 f32
    float*    Fold = bsv + HID;                            // 35*1024 f32

    k_fold<<<dim3(35, 4), 256, 0, stream>>>(obj_embed_W, dec1_W, Fold);

    int prep_elems = HID * KP + 48 * W2KP;
    k_prep<<<(prep_elems + 255) / 256, 256, 0, stream>>>(
        Fold, dec1_W, dec1_b, bn1k_g, bn1k_b, bn1k_m, bn1k_v, dec2_W,
        W1fT, W2T, bsv);

    k_main<<<BIMG, 256, 0, stream>>>(
        distribution, features, boxes, bn4_g, bn4_b, bn4_m, bn4_v, pos_W, pos_b,
        W1fT, W2T, bsv, dec2_b, out);
}